// Round 7
// baseline (529.484 us; speedup 1.0000x reference)
//
#include <hip/hip_runtime.h>
#include <stdint.h>

typedef short s16x4 __attribute__((ext_vector_type(4)));
typedef short s16x8 __attribute__((ext_vector_type(8)));
typedef float f32x4 __attribute__((ext_vector_type(4)));

#define MFMA16(a, b, c) __builtin_amdgcn_mfma_f32_16x16x32_bf16(a, b, c, 0, 0, 0)

__device__ __forceinline__ short f2bf(float f) {
  uint32_t u = __builtin_bit_cast(uint32_t, f);
  u += 0x7FFFu + ((u >> 16) & 1u);   // round-to-nearest-even
  return (short)(u >> 16);
}

// ---------------------------------------------------------------------------
// Weight pre-pack: bf16, MFMA fragment order (lane&15 = out-feature n,
// k = ks*32 + (lane>>4)*8 + e).  beta weights folded: bW' = bW + gW*fb[n]
// (fb = f0b for layer0, fhb[i] for residual layer i+1):
//   silu(gamma*(t+fb)+beta) == silu(gamma*t + (cf@bW' + beta_b'))
//   W0 frags 0..15, GB 16..111, WH 112..175, D1 176..191.  192 KiB in d_ws.
// ---------------------------------------------------------------------------
__global__ void pack_w(const float* __restrict__ w0, const float* __restrict__ wh,
                       const float* __restrict__ gw, const float* __restrict__ bw,
                       const float* __restrict__ d1, const float* __restrict__ f0b,
                       const float* __restrict__ fhb, short* __restrict__ out) {
  int idx = blockIdx.x * 512 + threadIdx.x;
  if (idx >= 98304) return;
  int f = idx >> 9;
  int r = idx & 511;
  int lane = r >> 3, e = r & 7;
  int kk = ((lane >> 4) << 3) + e;
  int nn = lane & 15;
  float v;
  if (f < 16) {                        // W0 (K padded 49->64)
    int ct = f >> 1, ks = f & 1;
    int k = ks * 32 + kk, n = ct * 16 + nn;
    if (k < 48) v = w0[(1 + k) * 128 + n];
    else if (k == 48) v = w0[n];
    else v = 0.f;
  } else if (f < 112) {                // GB (gamma / folded-beta)
    int f2 = f - 16;
    int ks = f2 & 1, ct = (f2 >> 1) & 7, gb = (f2 >> 4) & 1, l = f2 >> 5;
    int k = ks * 32 + kk, n = ct * 16 + nn;
    size_t off = (size_t)(l * 64 + k) * 128 + n;
    if (gb) {
      float fb = (l == 0) ? f0b[n] : fhb[(l - 1) * 128 + n];
      v = bw[off] + gw[off] * fb;
    } else v = gw[off];
  } else if (f < 176) {                // WH
    int f2 = f - 112;
    int ks = f2 & 3, ct = (f2 >> 2) & 7, i = f2 >> 5;
    int k = ks * 32 + kk, n = ct * 16 + nn;
    v = wh[(i * 128 + k) * 128 + n];
  } else {                             // D1
    int f2 = f - 176;
    int ks = f2 & 3, ct = f2 >> 2;
    int k = ks * 32 + kk, n = ct * 16 + nn;
    v = d1[k * 64 + n];
  }
  out[idx] = f2bf(v);
}

// ---------------------------------------------------------------------------
// R7 main kernel: zero-barrier wave slabs (R6 structure, transpose FIXED).
// mfma(W_frag, x_frag) computes (x@W)^T: D col(l15) = point row, D row
// (g16*4+rr) = feature-within-tile.  Each wave owns 16 point-rows end-to-end.
// Transpose buffer layout (FIX): POINT-major [16][132]:
//   element (feature f, point p) at xw[p*132 + f]
//   store: lane(g16,l15) writes f = ct*16 + g16*4 + rr of point l15
//          -> s16x4 at xw[l15*132 + ct*16 + g16*4]   (rr contiguous)
//   load:  lane(g16,l15) reads x[point l15][k = ks*32 + g16*8 + e]
//          -> two b64 at xw[l15*132 + ks*32 + g16*8] (+4)
// Both spread exactly 4 dword-accesses per bank (structural minimum).
// Explicit lgkmcnt(0) fence between store and load (cross-lane in-wave).
// ---------------------------------------------------------------------------
__global__ __launch_bounds__(256) void ngc_main(
    const float* __restrict__ coords, const float* __restrict__ angles,
    const float* __restrict__ rho, const float* __restrict__ rho_n,
    const float* __restrict__ cf, const float* __restrict__ ts,
    const float* __restrict__ gt0, const float* __restrict__ gr0,
    const float* __restrict__ gt1, const float* __restrict__ gr1,
    const float* __restrict__ gt2, const float* __restrict__ gr2,
    const float* __restrict__ f0b, const float* __restrict__ fhb,
    const float* __restrict__ gab, const float* __restrict__ beb,
    const float* __restrict__ d1b, const float* __restrict__ d2w,
    const float* __restrict__ d2b, const short* __restrict__ pw,
    float* __restrict__ out, int n, int nwt) {
  __shared__ __align__(16) float bias_lds[1024];   // l*2={ga,be'} *128; 768 d1b; 832 d2w
  __shared__ __align__(16) short xT[4][16 * 132];  // per-wave transpose buf

  const int tid = threadIdx.x;
  const int lane = tid & 63;
  const int w = tid >> 6;
  const int g16 = lane >> 4;
  const int l15 = lane & 15;

  // ---- bias staging (once per block; the only barrier) --------------------
  for (int idx = tid; idx < 896; idx += 256) {
    float v;
    if (idx < 768) {
      int arr = idx >> 7, c = idx & 127, l = arr >> 1;
      if (arr & 1) {
        float fb = (l == 0) ? f0b[c] : fhb[(l - 1) * 128 + c];
        v = beb[l * 128 + c] + gab[l * 128 + c] * fb;
      } else v = gab[l * 128 + c];
    } else if (idx < 832) v = d1b[idx - 768];
    else v = d2w[idx - 832];
    bias_lds[idx] = v;
  }
  __syncthreads();

  int wt = blockIdx.x * 4 + w;
  if (wt >= nwt) wt = nwt - 1;       // duplicate of last slab; same values stored
  const int row0w = wt * 16;
  int grow = row0w + l15; if (grow >= n) grow = n - 1;

  // ---- ts preload: 32 f32 (this lane's row l15, features ct*16+g16*4+rr) -
  float tsr[8][4];
  {
    const float* tsp = ts + (size_t)grow * 128 + g16 * 4;
#pragma unroll
    for (int ct = 0; ct < 8; ++ct)
#pragma unroll
      for (int rr = 0; rr < 4; ++rr) tsr[ct][rr] = tsp[ct * 16 + rr];
  }

  // ---- cf B-frags: lane holds cf[row l15][k = ks*32 + g16*8 + e] ---------
  s16x8 cfF0, cfF1;
  {
    const float* cfr = cf + (size_t)grow * 64 + g16 * 8;
    float4 a0 = *(const float4*)(cfr);
    float4 a1 = *(const float4*)(cfr + 4);
    float4 b0 = *(const float4*)(cfr + 32);
    float4 b1 = *(const float4*)(cfr + 36);
    cfF0 = (s16x8){f2bf(a0.x), f2bf(a0.y), f2bf(a0.z), f2bf(a0.w),
                   f2bf(a1.x), f2bf(a1.y), f2bf(a1.z), f2bf(a1.w)};
    cfF1 = (s16x8){f2bf(b0.x), f2bf(b0.y), f2bf(b0.z), f2bf(b0.w),
                   f2bf(b1.x), f2bf(b1.y), f2bf(b1.z), f2bf(b1.w)};
  }

  // ---- feat B-frags via per-lane bilinear gathers -------------------------
  float c_ = coords[grow], a_ = angles[grow], rn_ = rho_n[grow];
  auto gather8 = [&](const float* G, int Wg, float u, float v) -> s16x8 {
    float x = u * (float)(Wg - 1), y = v * (float)(Wg - 1);
    int ix = (int)x; ix = ix < 0 ? 0 : (ix > Wg - 2 ? Wg - 2 : ix);
    int iy = (int)y; iy = iy < 0 ? 0 : (iy > Wg - 2 ? Wg - 2 : iy);
    float wx = x - (float)ix, wy = y - (float)iy;
    const float4* p0 = (const float4*)(G + (size_t)(iy * Wg + ix) * 8);
    const float4* p1 = (const float4*)(G + (size_t)((iy + 1) * Wg + ix) * 8);
    float4 c00a = p0[0], c00b = p0[1], c01a = p0[2], c01b = p0[3];
    float4 c10a = p1[0], c10b = p1[1], c11a = p1[2], c11b = p1[3];
    float w00 = (1.f - wx) * (1.f - wy), w01 = wx * (1.f - wy);
    float w10 = (1.f - wx) * wy, w11 = wx * wy;
    s16x8 o;
    o[0] = f2bf(c00a.x * w00 + c01a.x * w01 + c10a.x * w10 + c11a.x * w11);
    o[1] = f2bf(c00a.y * w00 + c01a.y * w01 + c10a.y * w10 + c11a.y * w11);
    o[2] = f2bf(c00a.z * w00 + c01a.z * w01 + c10a.z * w10 + c11a.z * w11);
    o[3] = f2bf(c00a.w * w00 + c01a.w * w01 + c10a.w * w10 + c11a.w * w11);
    o[4] = f2bf(c00b.x * w00 + c01b.x * w01 + c10b.x * w10 + c11b.x * w11);
    o[5] = f2bf(c00b.y * w00 + c01b.y * w01 + c10b.y * w10 + c11b.y * w11);
    o[6] = f2bf(c00b.z * w00 + c01b.z * w01 + c10b.z * w10 + c11b.z * w11);
    o[7] = f2bf(c00b.w * w00 + c01b.w * w01 + c10b.w * w10 + c11b.w * w11);
    return o;
  };
  // featF0: k = g16*8 + e  -> grid g16 (gt0,gt1,gt2,gr0)
  const float* G0 = (g16 == 0) ? gt0 : (g16 == 1) ? gt1 : (g16 == 2) ? gt2 : gr0;
  int W0g = (g16 < 3) ? (128 << g16) : 128;
  float u0 = (g16 < 3) ? a_ : rn_;
  s16x8 featF0 = gather8(G0, W0g, u0, c_);
  // featF1: k = 32 + g16*8 + e -> g16<2: gr1/gr2; g16==2: rho at e0; g16==3: 0
  s16x8 featF1;
  if (g16 < 2) {
    featF1 = gather8(g16 == 0 ? gr1 : gr2, 256 << g16, rn_, c_);
  } else if (g16 == 2) {
    featF1 = (s16x8){f2bf(rho[grow]), 0, 0, 0, 0, 0, 0, 0};
  } else {
    featF1 = (s16x8){0, 0, 0, 0, 0, 0, 0, 0};
  }

  auto ldw = [&](int frag) -> s16x8 { return ((const s16x8*)pw)[frag * 64 + lane]; };
  short* xw = &xT[w][0];
  auto xstore = [&](const f32x4* acc) {
#pragma unroll
    for (int ct = 0; ct < 8; ++ct) {
      s16x4 sv = { f2bf(acc[ct][0]), f2bf(acc[ct][1]),
                   f2bf(acc[ct][2]), f2bf(acc[ct][3]) };
      *(s16x4*)&xw[l15 * 132 + ct * 16 + g16 * 4] = sv;
    }
  };
  s16x8 xF[4];
  auto xload = [&]() {
    asm volatile("s_waitcnt lgkmcnt(0)" ::: "memory");   // cross-lane via LDS
#pragma unroll
    for (int ks = 0; ks < 4; ++ks) {
      s16x4 lo = *(const s16x4*)&xw[l15 * 132 + ks * 32 + g16 * 8];
      s16x4 hi = *(const s16x4*)&xw[l15 * 132 + ks * 32 + g16 * 8 + 4];
      xF[ks] = (s16x8){lo[0], lo[1], lo[2], lo[3], hi[0], hi[1], hi[2], hi[3]};
    }
  };

  f32x4 acc[8];

  // ---- Layer 0: acc = silu(ga*t + be') + ts ------------------------------
#pragma unroll
  for (int ct = 0; ct < 8; ++ct) {
    s16x8 w0a = ldw(ct * 2), w0b = ldw(ct * 2 + 1);
    s16x8 gaa = ldw(16 + ct * 2), gab_ = ldw(16 + ct * 2 + 1);
    s16x8 bea = ldw(32 + ct * 2), beb_ = ldw(32 + ct * 2 + 1);
    f32x4 t = {0.f, 0.f, 0.f, 0.f};
    t = MFMA16(w0a, featF0, t); t = MFMA16(w0b, featF1, t);
    f32x4 ga = {0.f, 0.f, 0.f, 0.f};
    ga = MFMA16(gaa, cfF0, ga); ga = MFMA16(gab_, cfF1, ga);
    f32x4 be = {0.f, 0.f, 0.f, 0.f};
    be = MFMA16(bea, cfF0, be); be = MFMA16(beb_, cfF1, be);
    f32x4 gb_ = *(const f32x4*)&bias_lds[ct * 16 + g16 * 4];
    f32x4 bb_ = *(const f32x4*)&bias_lds[128 + ct * 16 + g16 * 4];
#pragma unroll
    for (int rr = 0; rr < 4; ++rr) {
      float z = (ga[rr] + gb_[rr]) * t[rr] + (be[rr] + bb_[rr]);
      acc[ct][rr] = z * __builtin_amdgcn_rcpf(1.f + __expf(-z)) + tsr[ct][rr];
    }
  }
  xstore(acc);
  xload();

  // ---- Residual FiLM blocks (wave-private, no barriers) ------------------
#pragma unroll
  for (int i = 0; i < 2; ++i) {
#pragma unroll
    for (int ct = 0; ct < 8; ++ct) {
      s16x8 h0 = ldw(112 + i * 32 + ct * 4);
      s16x8 h1 = ldw(112 + i * 32 + ct * 4 + 1);
      s16x8 h2 = ldw(112 + i * 32 + ct * 4 + 2);
      s16x8 h3 = ldw(112 + i * 32 + ct * 4 + 3);
      s16x8 gaa = ldw(16 + (i + 1) * 32 + ct * 2);
      s16x8 gab_ = ldw(16 + (i + 1) * 32 + ct * 2 + 1);
      s16x8 bea = ldw(16 + (i + 1) * 32 + 16 + ct * 2);
      s16x8 beb_ = ldw(16 + (i + 1) * 32 + 16 + ct * 2 + 1);
      f32x4 t = {0.f, 0.f, 0.f, 0.f};
      t = MFMA16(h0, xF[0], t); t = MFMA16(h1, xF[1], t);
      t = MFMA16(h2, xF[2], t); t = MFMA16(h3, xF[3], t);
      f32x4 ga = {0.f, 0.f, 0.f, 0.f};
      ga = MFMA16(gaa, cfF0, ga); ga = MFMA16(gab_, cfF1, ga);
      f32x4 be = {0.f, 0.f, 0.f, 0.f};
      be = MFMA16(bea, cfF0, be); be = MFMA16(beb_, cfF1, be);
      f32x4 gb_ = *(const f32x4*)&bias_lds[(i + 1) * 256 + ct * 16 + g16 * 4];
      f32x4 bb_ = *(const f32x4*)&bias_lds[(i + 1) * 256 + 128 + ct * 16 + g16 * 4];
#pragma unroll
      for (int rr = 0; rr < 4; ++rr) {
        float z = (ga[rr] + gb_[rr]) * t[rr] + (be[rr] + bb_[rr]);
        acc[ct][rr] += z * __builtin_amdgcn_rcpf(1.f + __expf(-z));
      }
    }
    xstore(acc);
    xload();
  }

  // ---- Decoder: sdf = relu(x@W1+b1)@W2 + b2 ------------------------------
  float sdfp = 0.f;
#pragma unroll
  for (int ct = 0; ct < 4; ++ct) {
    s16x8 d0 = ldw(176 + ct * 4), d1_ = ldw(176 + ct * 4 + 1);
    s16x8 d2_ = ldw(176 + ct * 4 + 2), d3_ = ldw(176 + ct * 4 + 3);
    f32x4 t = {0.f, 0.f, 0.f, 0.f};
    t = MFMA16(d0, xF[0], t); t = MFMA16(d1_, xF[1], t);
    t = MFMA16(d2_, xF[2], t); t = MFMA16(d3_, xF[3], t);
    f32x4 db = *(const f32x4*)&bias_lds[768 + ct * 16 + g16 * 4];
    f32x4 wv = *(const f32x4*)&bias_lds[832 + ct * 16 + g16 * 4];
#pragma unroll
    for (int rr = 0; rr < 4; ++rr)
      sdfp += fmaxf(t[rr] + db[rr], 0.f) * wv[rr];
  }
  sdfp += __shfl_xor(sdfp, 16);
  sdfp += __shfl_xor(sdfp, 32);
  if (g16 == 0) {
    int gr = row0w + l15;
    if (gr < n) out[gr] = sdfp + d2b[0];
  }
}

extern "C" void kernel_launch(void* const* d_in, const int* in_sizes, int n_in,
                              void* d_out, int out_size, void* d_ws, size_t ws_size,
                              hipStream_t stream) {
  int n = in_sizes[0];
  short* pw = (short*)d_ws;   // needs 192 KiB
  pack_w<<<192, 512, 0, stream>>>(
      (const float*)d_in[12],  // film0_fcW
      (const float*)d_in[14],  // filmh_fcW
      (const float*)d_in[16],  // gammaW
      (const float*)d_in[18],  // betaW
      (const float*)d_in[20],  // decW1
      (const float*)d_in[13],  // film0_fcb (beta fold)
      (const float*)d_in[15],  // filmh_fcb (beta fold)
      pw);
  int nwt = (n + 15) / 16;
  int nb = (nwt + 3) / 4;
  ngc_main<<<nb, 256, 0, stream>>>(
      (const float*)d_in[0],   // coords
      (const float*)d_in[1],   // angles
      (const float*)d_in[2],   // rho
      (const float*)d_in[3],   // rho_n
      (const float*)d_in[4],   // curve_feats
      (const float*)d_in[5],   // type_sample
      (const float*)d_in[6],   // gt0
      (const float*)d_in[7],   // gr0   (dict order: per level gt, gr)
      (const float*)d_in[8],   // gt1
      (const float*)d_in[9],   // gr1
      (const float*)d_in[10],  // gt2
      (const float*)d_in[11],  // gr2
      (const float*)d_in[13],  // film0_fcb
      (const float*)d_in[15],  // filmh_fcb
      (const float*)d_in[17],  // gammab
      (const float*)d_in[19],  // betab
      (const float*)d_in[21],  // decb1
      (const float*)d_in[22],  // decW2
      (const float*)d_in[23],  // decb2
      pw, (float*)d_out, n, nwt);
}

// Round 8
// 302.740 us; speedup vs baseline: 1.7490x; 1.7490x over previous
//
#include <hip/hip_runtime.h>
#include <stdint.h>

typedef short s16x8 __attribute__((ext_vector_type(8)));
typedef float f32x4 __attribute__((ext_vector_type(4)));

#define MFMA16(a, b, c) __builtin_amdgcn_mfma_f32_16x16x32_bf16(a, b, c, 0, 0, 0)

__device__ __forceinline__ short f2bf(float f) {
  uint32_t u = __builtin_bit_cast(uint32_t, f);
  u += 0x7FFFu + ((u >> 16) & 1u);   // round-to-nearest-even
  return (short)(u >> 16);
}

// ---------------------------------------------------------------------------
// Weight pre-pack (R4 version, unchanged): bf16, MFMA B-fragment order.
// k = ks*32 + (lane>>4)*8 + e, n = ct*16 + (lane&15).
//   W0 frags 0..15, GB 16..111, WH 112..175, D1 176..191.  192 KiB in d_ws.
// ---------------------------------------------------------------------------
__global__ void pack_w(const float* __restrict__ w0, const float* __restrict__ wh,
                       const float* __restrict__ gw, const float* __restrict__ bw,
                       const float* __restrict__ d1, short* __restrict__ out) {
  int idx = blockIdx.x * 512 + threadIdx.x;
  if (idx >= 98304) return;
  int f = idx >> 9;
  int r = idx & 511;
  int lane = r >> 3, e = r & 7;
  int kk = ((lane >> 4) << 3) + e;
  int nn = lane & 15;
  float v;
  if (f < 16) {
    int ct = f >> 1, ks = f & 1;
    int k = ks * 32 + kk, n = ct * 16 + nn;
    if (k < 48) v = w0[(1 + k) * 128 + n];
    else if (k == 48) v = w0[n];
    else v = 0.f;
  } else if (f < 112) {
    int f2 = f - 16;
    int ks = f2 & 1, ct = (f2 >> 1) & 7, gb = (f2 >> 4) & 1, l = f2 >> 5;
    int k = ks * 32 + kk, n = ct * 16 + nn;
    const float* Wp = gb ? bw : gw;
    v = Wp[(l * 64 + k) * 128 + n];
  } else if (f < 176) {
    int f2 = f - 112;
    int ks = f2 & 3, ct = (f2 >> 2) & 7, i = f2 >> 5;
    int k = ks * 32 + kk, n = ct * 16 + nn;
    v = wh[(i * 128 + k) * 128 + n];
  } else {
    int f2 = f - 176;
    int ks = f2 & 3, ct = f2 >> 2;
    int k = ks * 32 + kk, n = ct * 16 + nn;
    v = d1[k * 64 + n];
  }
  out[idx] = f2bf(v);
}

// ---------------------------------------------------------------------------
// R8 main kernel: R4 structure at HALF block size for 2x barrier domains/CU.
// 256 threads (4 waves), 32 rows/block, 16.5 KiB LDS -> 8 blocks/CU
// (32 waves/CU, wave-capped).  Wave w owns col-tiles ct = w and w+4.
// Residual state f32 in registers xr[2][2][4]; LDS xA single buffer updated
// in place with read->bar->write->bar (R0/R4-proven).  Dedicated red region.
// Frag-linear LDS: frag f at [f*1024,+1024), lane l at +l*16; element
// (row,col): frag=(row>>4)*KS+(col>>5), slot=((col>>3)&3)*16+(row&15),
// byte=(col&7)*2.  ts prefetched at entry (overlaps gather/cf loads).
// ---------------------------------------------------------------------------
__global__ __launch_bounds__(256) void ngc_main(
    const float* __restrict__ coords, const float* __restrict__ angles,
    const float* __restrict__ rho, const float* __restrict__ rho_n,
    const float* __restrict__ cf, const float* __restrict__ ts,
    const float* __restrict__ gt0, const float* __restrict__ gr0,
    const float* __restrict__ gt1, const float* __restrict__ gr1,
    const float* __restrict__ gt2, const float* __restrict__ gr2,
    const float* __restrict__ f0b, const float* __restrict__ fhb,
    const float* __restrict__ gab, const float* __restrict__ beb,
    const float* __restrict__ d1b, const float* __restrict__ d2w,
    const float* __restrict__ d2b, const short* __restrict__ pw,
    float* __restrict__ out, int n) {
  __shared__ __align__(16) char smem[17 * 1024];
  char* featA = smem;               // 4 KiB: frag = rg*2+ks (rg<2, ks<2)
  char* cfA   = smem + 4 * 1024;    // 4 KiB: frag = rg*2+ks
  char* xA    = smem + 8 * 1024;    // 8 KiB: frag = rg*4+ks (ks<4)
  float* red  = (float*)(smem + 16 * 1024);  // 0.5 KiB, dedicated

  const int tid = threadIdx.x;
  const int lane = tid & 63;
  const int w = tid >> 6;           // wave id 0..3
  const int g16 = lane >> 4;
  const int l15 = lane & 15;
  const int row0 = blockIdx.x * 32;

  // ---- ts prefetch: 16 scalar f32 (2 col-tiles x 2 rg x 4 rr) ------------
  float tsr[2][2][4];
#pragma unroll
  for (int ct2 = 0; ct2 < 2; ++ct2) {
    int col = (w + ct2 * 4) * 16 + l15;
#pragma unroll
    for (int rg = 0; rg < 2; ++rg)
#pragma unroll
      for (int rr = 0; rr < 4; ++rr) {
        int grow = row0 + rg * 16 + g16 * 4 + rr; grow = grow < n ? grow : n - 1;
        tsr[ct2][rg][rr] = ts[(size_t)grow * 128 + col];
      }
  }

  // ---- bilinear gathers: 192 tasks (32 rows x 6 grids) -------------------
  if (tid < 192) {
    int r = tid & 31, g = tid >> 5;
    int gr_ = row0 + r; gr_ = gr_ < n ? gr_ : n - 1;
    float vv = coords[gr_];
    float u = (g < 3) ? angles[gr_] : rho_n[gr_];
    int lvl = (g < 3) ? g : g - 3;
    const float* G = (g == 0) ? gt0 : (g == 1) ? gt1 : (g == 2) ? gt2
                   : (g == 3) ? gr0 : (g == 4) ? gr1 : gr2;
    int Wg = 128 << lvl;
    float x = u * (float)(Wg - 1), y = vv * (float)(Wg - 1);
    int ix = (int)x; ix = ix < 0 ? 0 : (ix > Wg - 2 ? Wg - 2 : ix);
    int iy = (int)y; iy = iy < 0 ? 0 : (iy > Wg - 2 ? Wg - 2 : iy);
    float wx = x - (float)ix, wy = y - (float)iy;
    const float4* p0 = (const float4*)(G + (size_t)(iy * Wg + ix) * 8);
    const float4* p1 = (const float4*)(G + (size_t)((iy + 1) * Wg + ix) * 8);
    float4 c00a = p0[0], c00b = p0[1], c01a = p0[2], c01b = p0[3];
    float4 c10a = p1[0], c10b = p1[1], c11a = p1[2], c11b = p1[3];
    float w00 = (1.f - wx) * (1.f - wy), w01 = wx * (1.f - wy);
    float w10 = (1.f - wx) * wy, w11 = wx * wy;
    s16x8 o;
    o[0] = f2bf(c00a.x * w00 + c01a.x * w01 + c10a.x * w10 + c11a.x * w11);
    o[1] = f2bf(c00a.y * w00 + c01a.y * w01 + c10a.y * w10 + c11a.y * w11);
    o[2] = f2bf(c00a.z * w00 + c01a.z * w01 + c10a.z * w10 + c11a.z * w11);
    o[3] = f2bf(c00a.w * w00 + c01a.w * w01 + c10a.w * w10 + c11a.w * w11);
    o[4] = f2bf(c00b.x * w00 + c01b.x * w01 + c10b.x * w10 + c11b.x * w11);
    o[5] = f2bf(c00b.y * w00 + c01b.y * w01 + c10b.y * w10 + c11b.y * w11);
    o[6] = f2bf(c00b.z * w00 + c01b.z * w01 + c10b.z * w10 + c11b.z * w11);
    o[7] = f2bf(c00b.w * w00 + c01b.w * w01 + c10b.w * w10 + c11b.w * w11);
    int dst16 = ((r >> 4) * 2 + (g >> 2)) * 64 + (g & 3) * 16 + (r & 15);
    *(s16x8*)(featA + dst16 * 16) = o;
  }

  // ---- curve_feats -> cfA (bf16, frag-linear): 256 tasks -----------------
  {
    int cb = tid & 7, r = tid >> 3;
    int gr_ = row0 + r; gr_ = gr_ < n ? gr_ : n - 1;
    const float4* cp = (const float4*)(cf + (size_t)gr_ * 64 + cb * 8);
    float4 v0 = cp[0], v1 = cp[1];
    s16x8 s = { f2bf(v0.x), f2bf(v0.y), f2bf(v0.z), f2bf(v0.w),
                f2bf(v1.x), f2bf(v1.y), f2bf(v1.z), f2bf(v1.w) };
    int dst16 = ((r >> 4) * 2 + (cb >> 2)) * 64 + (cb & 3) * 16 + (r & 15);
    *(s16x8*)(cfA + dst16 * 16) = s;
  }

  // ---- rho into feat col 48, zeros 49..63 --------------------------------
  if (tid < 32) {
    int r = tid;
    int gr_ = row0 + r; gr_ = gr_ < n ? gr_ : n - 1;
    s16x8 a = { f2bf(rho[gr_]), 0, 0, 0, 0, 0, 0, 0 };
    s16x8 z = { 0, 0, 0, 0, 0, 0, 0, 0 };
    int base = ((r >> 4) * 2 + 1) * 64;
    *(s16x8*)(featA + (base + 32 + (r & 15)) * 16) = a;
    *(s16x8*)(featA + (base + 48 + (r & 15)) * 16) = z;
  }
  __syncthreads();

  auto ldF = [&](const char* b, int frag) -> s16x8 {
    return *(const s16x8*)(b + (frag * 64 + lane) * 16);
  };
  auto ldw = [&](int frag) -> s16x8 { return ((const s16x8*)pw)[frag * 64 + lane]; };

  float xr[2][2][4];

  // ---- Layer 0: xr = silu(g0*(feat@W0+b0)+be0) + ts; xA = bf16(xr) -------
#pragma unroll
  for (int ct2 = 0; ct2 < 2; ++ct2) {
    int ct = w + ct2 * 4;
    int col = ct * 16 + l15;
    s16x8 bw0 = ldw(ct * 2), bw1 = ldw(ct * 2 + 1);
    s16x8 bg0 = ldw(16 + ct * 2), bg1 = ldw(16 + ct * 2 + 1);
    s16x8 bb0 = ldw(32 + ct * 2), bb1 = ldw(32 + ct * 2 + 1);
    float f0bv = f0b[col], gabv = gab[col], bebv = beb[col];
    int cbase = col >> 5, cslot = ((col >> 3) & 3) * 16, ce = (col & 7) * 2;
#pragma unroll
    for (int rg = 0; rg < 2; ++rg) {
      s16x8 a0 = ldF(featA, rg * 2), a1 = ldF(featA, rg * 2 + 1);
      s16x8 c0 = ldF(cfA, rg * 2), c1 = ldF(cfA, rg * 2 + 1);
      f32x4 t = {0.f, 0.f, 0.f, 0.f};
      t = MFMA16(a0, bw0, t); t = MFMA16(a1, bw1, t);
      f32x4 ga = {0.f, 0.f, 0.f, 0.f};
      ga = MFMA16(c0, bg0, ga); ga = MFMA16(c1, bg1, ga);
      f32x4 be = {0.f, 0.f, 0.f, 0.f};
      be = MFMA16(c0, bb0, be); be = MFMA16(c1, bb1, be);
      char* xbase = xA + (rg * 4 + cbase) * 1024 + ce;
#pragma unroll
      for (int rr = 0; rr < 4; ++rr) {
        float z = (ga[rr] + gabv) * (t[rr] + f0bv) + (be[rr] + bebv);
        float sl = z * __builtin_amdgcn_rcpf(1.f + __expf(-z));
        xr[ct2][rg][rr] = sl + tsr[ct2][rg][rr];
        *(short*)(xbase + (cslot + g16 * 4 + rr) * 16) = f2bf(xr[ct2][rg][rr]);
      }
    }
  }
  __syncthreads();

  // ---- Residual FiLM blocks: read xA -> barrier -> write xA -> barrier ---
#pragma unroll
  for (int i = 0; i < 2; ++i) {
    f32x4 zs[2][2];
#pragma unroll
    for (int ct2 = 0; ct2 < 2; ++ct2) {
      int ct = w + ct2 * 4;
      int col = ct * 16 + l15;
      s16x8 bh0 = ldw(112 + i * 32 + ct * 4);
      s16x8 bh1 = ldw(112 + i * 32 + ct * 4 + 1);
      s16x8 bh2 = ldw(112 + i * 32 + ct * 4 + 2);
      s16x8 bh3 = ldw(112 + i * 32 + ct * 4 + 3);
      s16x8 bg0 = ldw(16 + (i + 1) * 32 + ct * 2);
      s16x8 bg1 = ldw(16 + (i + 1) * 32 + ct * 2 + 1);
      s16x8 bb0 = ldw(16 + (i + 1) * 32 + 16 + ct * 2);
      s16x8 bb1 = ldw(16 + (i + 1) * 32 + 16 + ct * 2 + 1);
      float fhbv = fhb[i * 128 + col];
      float gabv = gab[(i + 1) * 128 + col];
      float bebv = beb[(i + 1) * 128 + col];
#pragma unroll
      for (int rg = 0; rg < 2; ++rg) {
        s16x8 xa = ldF(xA, rg * 4), xb = ldF(xA, rg * 4 + 1);
        s16x8 xc = ldF(xA, rg * 4 + 2), xd = ldF(xA, rg * 4 + 3);
        s16x8 c0 = ldF(cfA, rg * 2), c1 = ldF(cfA, rg * 2 + 1);
        f32x4 t = {0.f, 0.f, 0.f, 0.f};
        t = MFMA16(xa, bh0, t); t = MFMA16(xb, bh1, t);
        t = MFMA16(xc, bh2, t); t = MFMA16(xd, bh3, t);
        f32x4 ga = {0.f, 0.f, 0.f, 0.f};
        ga = MFMA16(c0, bg0, ga); ga = MFMA16(c1, bg1, ga);
        f32x4 be = {0.f, 0.f, 0.f, 0.f};
        be = MFMA16(c0, bb0, be); be = MFMA16(c1, bb1, be);
        f32x4 z;
#pragma unroll
        for (int rr = 0; rr < 4; ++rr) {
          float zz = (ga[rr] + gabv) * (t[rr] + fhbv) + (be[rr] + bebv);
          z[rr] = zz * __builtin_amdgcn_rcpf(1.f + __expf(-zz));
        }
        zs[ct2][rg] = z;
      }
    }
    __syncthreads();   // all waves' MFMA reads of xA complete
#pragma unroll
    for (int ct2 = 0; ct2 < 2; ++ct2) {
      int col = (w + ct2 * 4) * 16 + l15;
      int cbase = col >> 5, cslot = ((col >> 3) & 3) * 16, ce = (col & 7) * 2;
#pragma unroll
      for (int rg = 0; rg < 2; ++rg) {
        char* xbase = xA + (rg * 4 + cbase) * 1024 + ce;
#pragma unroll
        for (int rr = 0; rr < 4; ++rr) {
          xr[ct2][rg][rr] += zs[ct2][rg][rr];
          *(short*)(xbase + (cslot + g16 * 4 + rr) * 16) = f2bf(xr[ct2][rg][rr]);
        }
      }
    }
    __syncthreads();   // in-place writes complete
  }

  // ---- Decoder: relu(x@W1+b1)@W2+b2 (reads xA, writes dedicated red) -----
  {
    int dcol = w * 16 + l15;
    s16x8 bd0 = ldw(176 + w * 4), bd1 = ldw(176 + w * 4 + 1);
    s16x8 bd2 = ldw(176 + w * 4 + 2), bd3 = ldw(176 + w * 4 + 3);
    float d1bv = d1b[dcol], w2v = d2w[dcol];
#pragma unroll
    for (int rg = 0; rg < 2; ++rg) {
      s16x8 xa = ldF(xA, rg * 4), xb = ldF(xA, rg * 4 + 1);
      s16x8 xc = ldF(xA, rg * 4 + 2), xd = ldF(xA, rg * 4 + 3);
      f32x4 hh = {0.f, 0.f, 0.f, 0.f};
      hh = MFMA16(xa, bd0, hh); hh = MFMA16(xb, bd1, hh);
      hh = MFMA16(xc, bd2, hh); hh = MFMA16(xd, bd3, hh);
#pragma unroll
      for (int rr = 0; rr < 4; ++rr) {
        float h = fmaxf(hh[rr] + d1bv, 0.f) * w2v;
        h += __shfl_xor(h, 1);
        h += __shfl_xor(h, 2);
        h += __shfl_xor(h, 4);
        h += __shfl_xor(h, 8);
        if (l15 == 0) red[(rg * 16 + g16 * 4 + rr) * 4 + w] = h;
      }
    }
  }
  __syncthreads();
  if (tid < 32) {
    int grow = row0 + tid;
    if (grow < n)
      out[grow] = red[tid * 4 + 0] + red[tid * 4 + 1] + red[tid * 4 + 2] +
                  red[tid * 4 + 3] + d2b[0];
  }
}

extern "C" void kernel_launch(void* const* d_in, const int* in_sizes, int n_in,
                              void* d_out, int out_size, void* d_ws, size_t ws_size,
                              hipStream_t stream) {
  int n = in_sizes[0];
  short* pw = (short*)d_ws;   // needs 192 KiB
  pack_w<<<192, 512, 0, stream>>>(
      (const float*)d_in[12],  // film0_fcW
      (const float*)d_in[14],  // filmh_fcW
      (const float*)d_in[16],  // gammaW
      (const float*)d_in[18],  // betaW
      (const float*)d_in[20],  // decW1
      pw);
  int nb = (n + 31) / 32;
  ngc_main<<<nb, 256, 0, stream>>>(
      (const float*)d_in[0],   // coords
      (const float*)d_in[1],   // angles
      (const float*)d_in[2],   // rho
      (const float*)d_in[3],   // rho_n
      (const float*)d_in[4],   // curve_feats
      (const float*)d_in[5],   // type_sample
      (const float*)d_in[6],   // gt0
      (const float*)d_in[7],   // gr0   (dict order: per level gt, gr)
      (const float*)d_in[8],   // gt1
      (const float*)d_in[9],   // gr1
      (const float*)d_in[10],  // gt2
      (const float*)d_in[11],  // gr2
      (const float*)d_in[13],  // film0_fcb
      (const float*)d_in[15],  // filmh_fcb
      (const float*)d_in[17],  // gammab
      (const float*)d_in[19],  // betab
      (const float*)d_in[21],  // decb1
      (const float*)d_in[22],  // decW2
      (const float*)d_in[23],  // decb2
      pw, (float*)d_out, n);
}